// Round 2
// baseline (187.106 us; speedup 1.0000x reference)
//
#include <hip/hip_runtime.h>
#include <stdint.h>

#define B 8
#define NQ 100000
#define NCLS 10
#define NELEM 1000000        // elements per batch (NQ*NCLS)
#define NV4 250000           // float4 per batch
#define KTOP 100
#define NPTS 20
#define CAP 256              // max candidates in fast path; == THREADS (1 cand/thread).
                             // Poisson(159) > 256 ~ 1e-14 -> exact fallback, still correct.
#define THREADS 256
#define CBLOCKS 128          // collect blocks per batch
#define REG 64               // candidate slots per block region (exp ~1.25 cands/block)
#define T0 3.6f              // prefilter: count>3.6 ~ Poisson(159); P(<100)~1e-6; fallback exact

// Order-preserving monotone key for f32 (larger float <-> larger key)
__device__ __forceinline__ uint32_t fkey(float x) {
  uint32_t u = __float_as_uint(x);
  return (u & 0x80000000u) ? ~u : (u | 0x80000000u);
}

__device__ __forceinline__ uint64_t composite(float logit, uint32_t idx) {
  float s = 1.0f / (1.0f + expf(-logit));
  // sorts desc by sigmoid f32 bits, then asc by index (matches top_k tie rule)
  return ((uint64_t)__float_as_uint(s) << 32) | (uint64_t)(0xFFFFFFFFu - idx);
}

// Per-block private regions: NO global atomics, NO device fences.
// (R2: same-address atomic-with-return = 124us; R5: __threadfence handoff = 110us.)
// collect is HBM-bound: 32 MB cls read, float4-coalesced, 8-deep MLP. At its floor.
__global__ __launch_bounds__(THREADS)
void collect_kernel(const float* __restrict__ cls,
                    uint32_t* __restrict__ counts,   // [B*CBLOCKS]
                    uint64_t* __restrict__ cand) {   // [B*CBLOCKS][REG]
  __shared__ uint32_t lcnt;
  int b   = blockIdx.x / CBLOCKS;
  int sub = blockIdx.x % CBLOCKS;
  if (threadIdx.x == 0) lcnt = 0;
  __syncthreads();
  const float4* src = (const float4*)(cls + (size_t)b * NELEM);
  const int STRIDE = CBLOCKS * THREADS;            // 32768 float4s
  int base = sub * THREADS + threadIdx.x;
  // 8 strided loads up-front for memory-level parallelism
  float4 v[8];
  int   idx[8];
#pragma unroll
  for (int k = 0; k < 8; ++k) {
    idx[k] = base + k * STRIDE;
    v[k] = (idx[k] < NV4) ? src[idx[k]] : make_float4(-100.f, -100.f, -100.f, -100.f);
  }
  uint64_t* region = cand + (size_t)(b * CBLOCKS + sub) * REG;
#pragma unroll
  for (int k = 0; k < 8; ++k) {
    float xs[4] = {v[k].x, v[k].y, v[k].z, v[k].w};
#pragma unroll
    for (int l = 0; l < 4; ++l) {
      if (xs[l] > T0) {
        uint32_t slot = atomicAdd(&lcnt, 1u);      // LDS atomic, ~1-2 hits/block
        if (slot < REG)
          region[slot] = composite(xs[l], (uint32_t)(4 * idx[k] + l));
      }
    }
  }
  __syncthreads();
  if (threadIdx.x == 0) counts[b * CBLOCKS + sub] = lcnt;  // raw (>REG -> fallback)
}

// final v2: latency-restructured.
//  - shuffle scan (1 barrier) instead of Hillis-Steele LDS scan (14 barriers)
//  - candidate-region loads issued BEFORE the scan (HBM latency hides under it)
//  - rank-select fused with output gather: speculative bbox/pts loads issued
//    before the O(cnt) rank loop; rank-r thread writes row r straight from regs.
//    Deletes the s2 scatter + second exposed global round-trip.
//  3 barriers total on the fast path (was ~18).
//  v2.1: fallback binary-search midpoint computed in 64-bit (the 32-bit form
//  overflows at lo=0,hi=0xFFFFFFFF -> mid=lo -> infinite loop -> container hang).
__global__ __launch_bounds__(THREADS)
void final_kernel(const float* __restrict__ cls,
                  const float* __restrict__ bbox,
                  const float* __restrict__ pts,
                  const uint32_t* __restrict__ counts,
                  const uint64_t* __restrict__ cand,
                  float* __restrict__ out) {
  __shared__ uint64_t s[CAP];
  __shared__ uint32_t red[THREADS];      // fallback reduction scratch
  __shared__ uint32_t s_wtot[2];         // per-wave scan totals (CBLOCKS = 2 waves)
  __shared__ uint32_t s_badw[2];
  __shared__ uint32_t s_cnt;
  __shared__ float    s_smax;
  int b    = blockIdx.x;
  int tid  = threadIdx.x;
  int lane = tid & 63;
  int wv   = tid >> 6;

  // ---- phase A: counts + prefetch regions + shuffle scan (1 barrier) ----
  uint32_t rawc = 0, myc = 0, npf = 0;
  const uint64_t* region = nullptr;
  uint64_t pf0 = 0, pf1 = 0, pf2 = 0, pf3 = 0;
  if (tid < CBLOCKS) {
    rawc = counts[b * CBLOCKS + tid];
    myc = rawc > REG ? REG : rawc;
    region = cand + (size_t)(b * CBLOCKS + tid) * REG;
    npf = myc < 4u ? myc : 4u;           // covers P(Poisson(1.25)<=4) ~ 99.1% of regions
    if (npf > 0) pf0 = region[0];        // loads in flight during the scan below
    if (npf > 1) pf1 = region[1];
    if (npf > 2) pf2 = region[2];
    if (npf > 3) pf3 = region[3];
  }
  // intra-wave inclusive scan over myc (waves 0,1 carry CBLOCKS=128 entries)
  uint32_t v = myc;
#pragma unroll
  for (int d = 1; d < 64; d <<= 1) {
    uint32_t n = __shfl_up(v, d, 64);
    if (lane >= d) v += n;
  }
  uint64_t wbad = __ballot(rawc > REG);
  if (wv < 2) {
    if (lane == 63) s_wtot[wv] = v;
    if (lane == 0)  s_badw[wv] = (wbad != 0ull) ? 1u : 0u;
  }
  __syncthreads();
  uint32_t total = s_wtot[0] + s_wtot[1];
  bool bad = (s_badw[0] | s_badw[1]) || (total < KTOP) || (total > CAP);

  // ---- phase B: place candidates into s[] ----
  uint32_t cnt;
  if (!bad) {
    if (tid < CBLOCKS) {
      uint32_t off = (wv == 1 ? v + s_wtot[0] : v) - myc;   // exclusive prefix
      if (npf > 0) s[off + 0] = pf0;
      if (npf > 1) s[off + 1] = pf1;
      if (npf > 2) s[off + 2] = pf2;
      if (npf > 3) s[off + 3] = pf3;
      for (uint32_t j = npf; j < myc; ++j) s[off + j] = region[j];  // rare tail
    }
    cnt = total;
  } else {
    // exact fallback: binary-search the KTOP threshold over the raw logits.
    const float* src = cls + (size_t)b * NELEM;
    uint32_t lo = 0, hi = 0xFFFFFFFFu;
    while (lo < hi) {
      uint32_t mid = (uint32_t)(((uint64_t)lo + (uint64_t)hi + 1ull) >> 1);
      uint32_t c = 0;
      for (int i = tid; i < NELEM; i += THREADS)
        c += (fkey(src[i]) >= mid) ? 1u : 0u;
      red[tid] = c;
      __syncthreads();
      for (int off2 = THREADS / 2; off2 > 0; off2 >>= 1) {
        if (tid < off2) red[tid] += red[tid + off2];
        __syncthreads();
      }
      uint32_t totc = red[0];
      __syncthreads();
      if (totc >= KTOP) lo = mid; else hi = mid - 1;
    }
    uint32_t T = lo;
    if (tid == 0) s_cnt = 0;
    __syncthreads();
    for (int i = tid; i < NELEM; i += THREADS) {
      float x = src[i];
      if (fkey(x) > T) {
        uint32_t slot = atomicAdd(&s_cnt, 1u);    // LDS atomic, < KTOP hits
        s[slot] = composite(x, (uint32_t)i);
      }
    }
    __syncthreads();
    if (tid == 0) {
      uint32_t nGT = s_cnt, got = 0;
      for (int i = 0; i < NELEM && nGT + got < KTOP; ++i) {
        float x = src[i];
        if (fkey(x) == T) { s[nGT + got] = composite(x, (uint32_t)i); got++; }
      }
    }
    cnt = KTOP;
  }
  __syncthreads();

  // ---- phase C: speculative gather + rank (gather latency hides under rank loop) ----
  // cnt <= CAP == THREADS -> exactly one candidate per thread; composites unique,
  // rank = #larger, so ranks 0..cnt-1 are a permutation and every output row
  // r < KTOP is written by exactly one thread.
  bool have = (tid < (int)cnt);
  uint32_t r = 0, label = 0;
  float score = 0.f;
  float4 bb = make_float4(0.f, 0.f, 0.f, 0.f);
  float4 p[10];
  if (have) {
    uint64_t me = s[tid];
    score = __uint_as_float((uint32_t)(me >> 32));
    uint32_t idx = 0xFFFFFFFFu - (uint32_t)(me & 0xFFFFFFFFu);
    label = idx % NCLS;
    uint32_t bidx = idx / NCLS;
    if (bidx >= NQ) bidx = 0;  // safety
    // issue all gathers now; consumed after the rank loop + barrier
    bb = ((const float4*)(bbox + (size_t)b * NQ * 4))[bidx];
    const float4* ps = (const float4*)(pts + (size_t)b * NQ * NPTS * 2 +
                                       (size_t)bidx * NPTS * 2);
#pragma unroll
    for (int j = 0; j < 10; ++j) p[j] = ps[j];
    // rank among all candidates: cnt broadcast LDS reads (conflict-free)
    for (uint32_t j = 0; j < cnt; ++j) r += (s[j] > me) ? 1u : 0u;
    if (r == 0) s_smax = score;          // exactly one writer
  }
  __syncthreads();

  // ---- phase D: threshold-decay mask + transform + write (from registers) ----
  if (have && r < KTOP) {
    float smax = s_smax;
    int mode;       // 0: score > thr ; 1: score >= thr ; 2: all true
    float thr = 0.1f;
    if (smax > 0.1f) {
      mode = 0;
    } else {
      float tmp = 0.1f;
      mode = 2;
      while (true) {
        tmp *= 0.9f;
        if (tmp < 0.01f) { mode = 2; break; }
        if (smax >= tmp) { mode = 1; thr = tmp; break; }
      }
    }
    float hx = __fmul_rn(bb.z, 0.5f);
    float hy = __fmul_rn(bb.w, 0.5f);
    float x1 = __fadd_rn(__fmul_rn(__fsub_rn(bb.x, hx), 30.0f), -15.0f);
    float y1 = __fadd_rn(__fmul_rn(__fsub_rn(bb.y, hy), 60.0f), -30.0f);
    float x2 = __fadd_rn(__fmul_rn(__fadd_rn(bb.x, hx), 30.0f), -15.0f);
    float y2 = __fadd_rn(__fmul_rn(__fadd_rn(bb.y, hy), 60.0f), -30.0f);
    bool rmask = (x1 >= -20.0f) & (y1 >= -35.0f) & (x2 >= -20.0f) & (y2 >= -35.0f) &
                 (x1 <= 20.0f) & (y1 <= 35.0f) & (x2 <= 20.0f) & (y2 <= 35.0f);
    bool tmask = (mode == 2) || (mode == 0 ? (score > thr) : (score >= thr));
    bool mask = rmask && tmask;

    float* oBoxes  = out;                        // [B][K][4]
    float* oScores = out + B * KTOP * 4;         // [B][K]
    float* oLabels = oScores + B * KTOP;         // [B][K]
    float* oPts    = oLabels + B * KTOP;         // [B][K][NPTS][2]
    float* oMask   = oPts + B * KTOP * NPTS * 2; // [B][K]
    size_t rb = (size_t)b * KTOP + (size_t)r;

    ((float4*)oBoxes)[rb] = mask ? make_float4(x1, y1, x2, y2)
                                 : make_float4(0.f, 0.f, 0.f, 0.f);
    oScores[rb] = mask ? score : 0.0f;
    oLabels[rb] = mask ? (float)label : 0.0f;
    oMask[rb]   = mask ? 1.0f : 0.0f;

    float4* po = (float4*)(oPts + rb * NPTS * 2);
#pragma unroll
    for (int j = 0; j < 10; ++j) {
      float4 q = p[j];
      float4 o;
      o.x = __fadd_rn(__fmul_rn(q.x, 30.0f), -15.0f);
      o.y = __fadd_rn(__fmul_rn(q.y, 60.0f), -30.0f);
      o.z = __fadd_rn(__fmul_rn(q.z, 30.0f), -15.0f);
      o.w = __fadd_rn(__fmul_rn(q.w, 60.0f), -30.0f);
      po[j] = mask ? o : make_float4(0.f, 0.f, 0.f, 0.f);
    }
  }
}

extern "C" void kernel_launch(void* const* d_in, const int* in_sizes, int n_in,
                              void* d_out, int out_size, void* d_ws, size_t ws_size,
                              hipStream_t stream) {
  const float* cls  = (const float*)d_in[0];
  const float* bbox = (const float*)d_in[1];
  const float* pts  = (const float*)d_in[2];
  float* out = (float*)d_out;

  uint8_t* ws = (uint8_t*)d_ws;
  uint32_t* counts = (uint32_t*)ws;                        // B*CBLOCKS u32 = 4 KiB
  uint64_t* cand   = (uint64_t*)(ws + B * CBLOCKS * 4);    // B*CBLOCKS*REG u64 = 512 KiB

  collect_kernel<<<B * CBLOCKS, THREADS, 0, stream>>>(cls, counts, cand);
  final_kernel<<<B, THREADS, 0, stream>>>(cls, bbox, pts, counts, cand, out);
}